// Round 1
// baseline (4771.138 us; speedup 1.0000x reference)
//
#include <hip/hip_runtime.h>
#include <hip/hip_bf16.h>

// BatchTopKSAE: pre = relu((x - b_dec) @ W_enc + b_enc); per-row top-64 scatter.
// B=4096, D_IN=2048, D_SAE=65536, k=64 (k input is fixed by setup_inputs).
//
// Pipeline:
//  K1 prep_x      : xc = x - b_dec (fp32), x_bf = bf16(xc)
//  K2 transpose_w : Wt[n][k] = bf16(W[k][n])   (GEMM wants B^T = [N][K])
//  K3 gemm_bf16_8ph: pre[m][n] = relu(x_bf . Wt^T + b_enc)
//                   256x256 tile, BK=64, 8 waves, 8-phase/2-K-tiles schedule
//                   (T1 XCD swizzle + T2 LDS XOR swizzle + T3/T4 counted vmcnt + T5 setprio)
//  K4 select_cands: per row, histogram -> threshold; collect candidate cols (~140)
//  K5 bucket      : group (row,col,slot) pairs by 128-col tile of W
//  K6 recompute   : exact fp64 dot for every candidate (W read coalesced, LDS panel)
//  K7 topk_select : per-row bitonic sort of <=512 candidates on exact value, keep 64
//  K8 write_out   : zero row + scatter 64 exact values
//
// Scratch: big buffers live in d_out (disjoint lifetimes); small arrays in d_ws (~43 MiB).

#define D_IN   2048
#define D_SAE  65536
#define B_ROWS 4096
#define K_TOP  64
#define MAXC   512
#define NTILE  512   // D_SAE / 128

using bf16x8  = __attribute__((ext_vector_type(8))) __bf16;
using floatx4 = __attribute__((ext_vector_type(4))) float;

__device__ __forceinline__ unsigned short f2bf_rne(float f) {
  union { float f; unsigned u; } x; x.f = f;
  unsigned r = x.u + 0x7FFFu + ((x.u >> 16) & 1u);
  return (unsigned short)(r >> 16);
}

__device__ __forceinline__ void async_load16(const void* g, void* l) {
  __builtin_amdgcn_global_load_lds((const __attribute__((address_space(1))) void*)g,
                                   (__attribute__((address_space(3))) void*)l, 16, 0, 0);
}

// ---------------- K1: x - b_dec -> fp32 + bf16 ----------------
__global__ __launch_bounds__(256) void prep_x(const float* __restrict__ x,
                                              const float* __restrict__ b_dec,
                                              unsigned short* __restrict__ x_bf,
                                              float* __restrict__ xc) {
  int i4 = blockIdx.x * 256 + threadIdx.x;          // 2,097,152 float4s
  const float4* xv = (const float4*)x;
  float4 v = xv[i4];
  int kb = (i4 * 4) & (D_IN - 1);
  v.x -= b_dec[kb + 0]; v.y -= b_dec[kb + 1]; v.z -= b_dec[kb + 2]; v.w -= b_dec[kb + 3];
  ((float4*)xc)[i4] = v;
  ushort4 b;
  b.x = f2bf_rne(v.x); b.y = f2bf_rne(v.y); b.z = f2bf_rne(v.z); b.w = f2bf_rne(v.w);
  ((ushort4*)x_bf)[i4] = b;
}

// ---------------- K2: W[k][n] -> Wt[n][k] bf16 ----------------
__global__ __launch_bounds__(256) void transpose_w(const float* __restrict__ W,
                                                   unsigned short* __restrict__ Wt) {
  __shared__ float tile[64][65];
  int bn = blockIdx.x, bk = blockIdx.y;
  int t = threadIdx.x;
  int c = t & 63, r0 = t >> 6;
#pragma unroll
  for (int i = 0; i < 16; i++) {
    int r = r0 + i * 4;
    tile[r][c] = W[(size_t)(bk * 64 + r) * D_SAE + bn * 64 + c];
  }
  __syncthreads();
#pragma unroll
  for (int i = 0; i < 16; i++) {
    int r = r0 + i * 4;
    Wt[(size_t)(bn * 64 + r) * D_IN + bk * 64 + c] = f2bf_rne(tile[c][r]);
  }
}

// ---------------- K3: bf16 MFMA GEMM, 256^2 8-phase structure ----------------
// C[4096][65536] = A[M][K] * Bt[N][K]^T.
// 512 threads = 8 waves (2 M x 4 N), per-wave 128x64 output, BK=64, NT=32 K-tiles.
// LDS 128 KiB: A 2buf x [256][64] bf16 @0, B 2buf x [256][64] bf16 @64KiB.
//
// T2 swizzle: LDS byte(row, q) = row*128 + (q*16 ^ ((row&7)<<4)), q = 16B k-chunk.
//   global_load_lds writes linearly, so the swizzle is applied as the inverse
//   permutation on the GLOBAL source k-chunk (kc_src = q ^ (row&7)) and again on
//   the ds_read address (both-sides-or-neither, rule #21). Spreads the 16 rows of a
//   fragment read across all 8 16B slots of the 128B row -> 2 lanes/slot = free.
//
// Schedule per K-tile (4 phases, Gray quadrant order (0,0)(0,1)(1,1)(1,0)):
//   phase: ds_read changed-half frags | issue 1 half-tile prefetch (2 gloads)
//          | barrier | lgkmcnt(0) | setprio(1) 16 MFMA setprio(0) | barrier
// vmcnt ONCE per K-tile at phase 0, counted (vmcnt(2)): the 2 just-issued
// next-tile loads stay in flight across the barrier; never drain to 0 mid-loop.
#define GNT (D_IN / 64)   // 32 K-tiles

#define STAGE_A(kt, h, b) do { \
    const unsigned short* s_ = A + aRow + (size_t)(h) * 128 * D_IN + (size_t)(kt) * 64; \
    unsigned char* d_ = lds + (b) * 32768 + (h) * 16384 + t * 16; \
    async_load16(s_, d_); async_load16(s_ + 64 * D_IN, d_ + 8192); \
  } while (0)
#define STAGE_B(kt, h, b) do { \
    const unsigned short* s_ = Bt + bRow + (size_t)(h) * 128 * D_IN + (size_t)(kt) * 64; \
    unsigned char* d_ = lds + 65536 + (b) * 32768 + (h) * 16384 + t * 16; \
    async_load16(s_, d_); async_load16(s_ + 64 * D_IN, d_ + 8192); \
  } while (0)
#define LOAD_A(Mh) do { _Pragma("unroll") for (int i_ = 0; i_ < 4; ++i_) { \
    int o_ = baseA + (Mh) * 8192 + i_ * 2048; \
    aF[i_][0] = *(const bf16x8*)(lA + o_); \
    aF[i_][1] = *(const bf16x8*)(lA + (o_ ^ 64)); } } while (0)
#define LOAD_B(Nh) do { _Pragma("unroll") for (int j_ = 0; j_ < 2; ++j_) { \
    int o_ = baseB + (Nh) * 4096 + j_ * 2048; \
    bF[j_][0] = *(const bf16x8*)(lB + o_); \
    bF[j_][1] = *(const bf16x8*)(lB + (o_ ^ 64)); } } while (0)
#define MFMA_Q(Mh, Nh) do { \
    __builtin_amdgcn_s_setprio(1); \
    _Pragma("unroll") for (int i_ = 0; i_ < 4; ++i_) \
    _Pragma("unroll") for (int j_ = 0; j_ < 2; ++j_) { \
      acc[(Mh)*4+i_][(Nh)*2+j_] = __builtin_amdgcn_mfma_f32_16x16x32_bf16( \
          aF[i_][0], bF[j_][0], acc[(Mh)*4+i_][(Nh)*2+j_], 0, 0, 0); \
      acc[(Mh)*4+i_][(Nh)*2+j_] = __builtin_amdgcn_mfma_f32_16x16x32_bf16( \
          aF[i_][1], bF[j_][1], acc[(Mh)*4+i_][(Nh)*2+j_], 0, 0, 0); \
    } \
    __builtin_amdgcn_s_setprio(0); \
  } while (0)

__global__ __launch_bounds__(512, 2) void gemm_bf16_8ph(
    const unsigned short* __restrict__ A,
    const unsigned short* __restrict__ Bt,
    const float* __restrict__ b_enc,
    unsigned short* __restrict__ pre) {
  __shared__ __align__(16) unsigned char lds[131072];

  const int t = threadIdx.x;
  // T1: bijective XCD swizzle (4096 blocks, 4096 % 8 == 0). m-block fastest so each
  // XCD's 32 resident blocks sweep all 16 m-blocks of 2 consecutive N-panels:
  // each B-panel is read by exactly one XCD -> L2-local.
  const int orig = blockIdx.x;
  const int swz = (orig & 7) * 512 + (orig >> 3);
  const int mBase = (swz & 15) << 8;   // 16 m-blocks
  const int nBase = (swz >> 4) << 8;   // 256 n-blocks

  const int lane = t & 63, wave = t >> 6;
  const int wm = wave >> 2, wn = wave & 3;      // 2 x 4 waves, per-wave 128x64 C
  const int frow = lane & 15, khalf = lane >> 4;

  // staging map: half-tile = 128 rows x 64 cols bf16 = 1024 chunks of 16B; thread t
  // writes chunks t (row t>>3) and t+512 (row t>>3 + 64), LDS dest lane-linear.
  const int r0 = t >> 3, q0 = t & 7;
  const int kc0 = q0 ^ (r0 & 7);                // inverse T2 swizzle on global source
  const size_t aRow = (size_t)(mBase + r0) * D_IN + kc0 * 8;
  const size_t bRow = (size_t)(nBase + r0) * D_IN + kc0 * 8;

  // ds_read swizzle: byte = row*128 + ((ks*4+khalf)*16 ^ ((row&7)<<4)); row&7==frow&7
  const int qk0 = (khalf << 4) ^ ((frow & 7) << 4);
  const int baseA = (wm * 128 + frow) * 128 + qk0;
  const int baseB = (wn * 64 + frow) * 128 + qk0;

  floatx4 acc[8][4];
#pragma unroll
  for (int i = 0; i < 8; ++i)
#pragma unroll
    for (int j = 0; j < 4; ++j) acc[i][j] = (floatx4){0.f, 0.f, 0.f, 0.f};
  bf16x8 aF[4][2], bF[2][2];

  // prologue: stage K-tile 0 into buffer 0 (8 loads/thread)
  STAGE_A(0, 0, 0); STAGE_A(0, 1, 0); STAGE_B(0, 0, 0); STAGE_B(0, 1, 0);

#pragma unroll 1
  for (int tt = 0; tt < GNT; ++tt) {
    const int cur = tt & 1, nxt = cur ^ 1;
    const unsigned char* lA = lds + cur * 32768;
    const unsigned char* lB = lds + 65536 + cur * 32768;

    // ---- phase 0: quadrant (Mh=0, Nh=0); stage A-half0 of tt+1 -------------
    if (tt + 1 < GNT) {
      STAGE_A(tt + 1, 0, nxt);
      asm volatile("s_waitcnt vmcnt(2)" ::: "memory");  // retire tile tt's 8 loads
    } else {
      asm volatile("s_waitcnt vmcnt(0)" ::: "memory");  // final drain (once)
    }
    asm volatile("s_barrier" ::: "memory");             // all waves' loads landed
    LOAD_A(0); LOAD_B(0);
    asm volatile("s_waitcnt lgkmcnt(0)");
    MFMA_Q(0, 0);
    __builtin_amdgcn_s_barrier();

    // ---- phase 1: (0,1); stage A-half1 -------------------------------------
    LOAD_B(1);
    if (tt + 1 < GNT) STAGE_A(tt + 1, 1, nxt);
    __builtin_amdgcn_s_barrier();
    asm volatile("s_waitcnt lgkmcnt(0)");
    MFMA_Q(0, 1);
    __builtin_amdgcn_s_barrier();

    // ---- phase 2: (1,1); stage B-half0 -------------------------------------
    LOAD_A(1);
    if (tt + 1 < GNT) STAGE_B(tt + 1, 0, nxt);
    __builtin_amdgcn_s_barrier();
    asm volatile("s_waitcnt lgkmcnt(0)");
    MFMA_Q(1, 1);
    __builtin_amdgcn_s_barrier();

    // ---- phase 3: (1,0); stage B-half1 -------------------------------------
    LOAD_B(0);
    if (tt + 1 < GNT) STAGE_B(tt + 1, 1, nxt);
    __builtin_amdgcn_s_barrier();
    asm volatile("s_waitcnt lgkmcnt(0)");
    MFMA_Q(1, 0);
    __builtin_amdgcn_s_barrier();
  }

  // epilogue: C/D map col=lane&15, row=(lane>>4)*4+reg (m89-verified)
  const int ccol = lane & 15, crow = (lane >> 4) * 4;
#pragma unroll
  for (int j = 0; j < 4; ++j) {
    int n = nBase + wn * 64 + j * 16 + ccol;
    float be = b_enc[n];
#pragma unroll
    for (int i = 0; i < 8; ++i) {
#pragma unroll
      for (int v = 0; v < 4; ++v) {
        int m = mBase + wm * 128 + i * 16 + crow + v;
        float val = acc[i][j][v] + be;
        val = val > 0.f ? val : 0.f;                 // relu
        pre[(size_t)m * D_SAE + n] = f2bf_rne(val);
      }
    }
  }
}

#undef STAGE_A
#undef STAGE_B
#undef LOAD_A
#undef LOAD_B
#undef MFMA_Q

// ---------------- K4: per-row candidate selection ----------------
__global__ __launch_bounds__(256) void select_cands(const unsigned short* __restrict__ pre,
                                                    int* __restrict__ cand_idx,
                                                    int* __restrict__ cand_cnt) {
  __shared__ int hist[64];
  __shared__ float sT;
  __shared__ int scnt;
  int row = blockIdx.x, t = threadIdx.x;
  for (int i = t; i < 64; i += 256) hist[i] = 0;
  if (t == 0) scnt = 0;
  __syncthreads();
  const uint4* p = (const uint4*)(pre + (size_t)row * D_SAE);   // 8192 x 16B
  for (int i = t; i < 8192; i += 256) {
    uint4 w = p[i];
    unsigned wd[4] = {w.x, w.y, w.z, w.w};
#pragma unroll
    for (int e = 0; e < 4; e++) {
      unsigned lo = wd[e] << 16, hi = wd[e] & 0xFFFF0000u;
      float f0 = __uint_as_float(lo), f1 = __uint_as_float(hi);
      if (f0 >= 0.5f) atomicAdd(&hist[min((int)(lo >> 20) - 1008, 63)], 1);
      if (f1 >= 0.5f) atomicAdd(&hist[min((int)(hi >> 20) - 1008, 63)], 1);
    }
  }
  __syncthreads();
  if (t == 0) {
    int cum = 0, b = 63;
    for (; b >= 0; b--) { cum += hist[b]; if (cum >= K_TOP) break; }
    if (b < 0) b = 0;
    // bin floor minus margin: covers bf16-GEMM (~0.03 max) + bf16-store error
    sT = __uint_as_float((unsigned)(b + 1008) << 20) - 0.09f;
  }
  __syncthreads();
  float T = sT;
  for (int i = t; i < 8192; i += 256) {
    uint4 w = p[i];
    unsigned wd[4] = {w.x, w.y, w.z, w.w};
#pragma unroll
    for (int e = 0; e < 4; e++) {
      unsigned lo = wd[e] << 16, hi = wd[e] & 0xFFFF0000u;
      float f0 = __uint_as_float(lo), f1 = __uint_as_float(hi);
      if (f0 >= T) { int q = atomicAdd(&scnt, 1); if (q < MAXC) cand_idx[(size_t)row * MAXC + q] = i * 8 + e * 2; }
      if (f1 >= T) { int q = atomicAdd(&scnt, 1); if (q < MAXC) cand_idx[(size_t)row * MAXC + q] = i * 8 + e * 2 + 1; }
    }
  }
  __syncthreads();
  if (t == 0) cand_cnt[row] = min(scnt, MAXC);
}

// ---------------- K5: bucket candidates by 128-col tile ----------------
__global__ void zero_counts(int* tileCnt, int* cursor) {
  int i = blockIdx.x * 256 + threadIdx.x;
  if (i < NTILE) { tileCnt[i] = 0; cursor[i] = 0; }
}
__global__ __launch_bounds__(256) void count_pairs(const int* __restrict__ cand_idx,
                                                   const int* __restrict__ cand_cnt,
                                                   int* __restrict__ tileCnt) {
  int row = blockIdx.x, cnt = cand_cnt[row];
  for (int s = threadIdx.x; s < cnt; s += 256)
    atomicAdd(&tileCnt[cand_idx[(size_t)row * MAXC + s] >> 7], 1);
}
__global__ void scan_tiles(const int* __restrict__ tileCnt, int* __restrict__ tileOff) {
  if (threadIdx.x == 0) {
    int acc = 0;
    for (int i = 0; i < NTILE; i++) { tileOff[i] = acc; acc += tileCnt[i]; }
  }
}
__global__ __launch_bounds__(256) void scatter_pairs(const int* __restrict__ cand_idx,
                                                     const int* __restrict__ cand_cnt,
                                                     const int* __restrict__ tileOff,
                                                     int* __restrict__ cursor,
                                                     unsigned long long* __restrict__ pairs) {
  int row = blockIdx.x, cnt = cand_cnt[row];
  for (int s = threadIdx.x; s < cnt; s += 256) {
    int col = cand_idx[(size_t)row * MAXC + s];
    int tl = col >> 7;
    int q = atomicAdd(&cursor[tl], 1);
    pairs[tileOff[tl] + q] =
        ((unsigned long long)row << 32) | ((unsigned long long)(unsigned)col << 16) | (unsigned)s;
  }
}

// ---------------- K6: exact fp64 recompute of candidates ----------------
__global__ __launch_bounds__(256) void recompute_exact(const float* __restrict__ W,
                                                       const float* __restrict__ xc,
                                                       const float* __restrict__ b_enc,
                                                       const unsigned long long* __restrict__ pairs,
                                                       const int* __restrict__ tileCnt,
                                                       const int* __restrict__ tileOff,
                                                       double* __restrict__ candVal) {
  __shared__ float Wl[512 * 17];     // 512 k x 16 cols, pad 17 (bank-conflict free)
  __shared__ int lists[8][256];
  __shared__ int lcnt[8];
  __shared__ double pacc[256];
  int tile = blockIdx.x, t = threadIdx.x;
  int n0 = tile << 7;
  int nP = tileCnt[tile], base = tileOff[tile];
  if (t < 8) lcnt[t] = 0;
  __syncthreads();
  for (int i = t; i < nP; i += 256) {
    int col = (int)((pairs[base + i] >> 16) & 0xFFFF);
    int st = (col >> 4) & 7;
    int q = atomicAdd(&lcnt[st], 1);
    if (q < 256) lists[st][q] = i;
  }
  int lane = t & 63, wave = t >> 6;
  for (int st = 0; st < 8; st++) {
    __syncthreads();
    int cnt = min(lcnt[st], 256);
    for (int i = t; i < cnt; i += 256) pacc[i] = 0.0;
    for (int kc = 0; kc < 4; kc++) {
      __syncthreads();
      for (int e = t; e < 512 * 16; e += 256) {
        int k = e >> 4, c = e & 15;
        Wl[k * 17 + c] = W[(size_t)(kc * 512 + k) * D_SAE + n0 + st * 16 + c];
      }
      __syncthreads();
      for (int pi = wave; pi < cnt; pi += 4) {
        unsigned long long u = pairs[base + lists[st][pi]];
        int row = (int)(u >> 32);
        int cc = (int)((u >> 16) & 15);
        const float* xr = xc + (size_t)row * D_IN + kc * 512;
        double a = 0.0;
#pragma unroll
        for (int j = 0; j < 8; j++) {
          int k = lane + j * 64;
          a += (double)xr[k] * (double)Wl[k * 17 + cc];
        }
#pragma unroll
        for (int off = 32; off > 0; off >>= 1) a += __shfl_down(a, off, 64);
        if (lane == 0) pacc[pi] += a;
      }
    }
    __syncthreads();
    for (int i = t; i < cnt; i += 256) {
      unsigned long long u = pairs[base + lists[st][i]];
      int row = (int)(u >> 32);
      int col = (int)((u >> 16) & 0xFFFF);
      int slot = (int)(u & 0xFFFF);
      candVal[(size_t)row * MAXC + slot] = pacc[i] + (double)b_enc[col];
    }
  }
}

// ---------------- K7: per-row bitonic top-64 on exact values ----------------
__global__ __launch_bounds__(256) void topk_select(const int* __restrict__ cand_idx,
                                                   const int* __restrict__ cand_cnt,
                                                   const double* __restrict__ candVal,
                                                   int* __restrict__ topIdx,
                                                   float* __restrict__ topVal) {
  __shared__ double sv[MAXC];
  __shared__ int si[MAXC];
  int row = blockIdx.x, t = threadIdx.x;
  int cnt = cand_cnt[row];
  for (int i = t; i < MAXC; i += 256) {
    if (i < cnt) { sv[i] = candVal[(size_t)row * MAXC + i]; si[i] = cand_idx[(size_t)row * MAXC + i]; }
    else         { sv[i] = -1.0e300; si[i] = 0x7FFFFFFF; }
  }
  for (int ksz = 2; ksz <= MAXC; ksz <<= 1) {
    for (int j = ksz >> 1; j > 0; j >>= 1) {
      __syncthreads();
      for (int e = t; e < MAXC; e += 256) {
        int p = e ^ j;
        if (p > e) {
          double v0 = sv[e], v1 = sv[p];
          int i0 = si[e], i1 = si[p];
          bool before = (v0 > v1) || (v0 == v1 && i0 < i1);   // e precedes p in desc order
          bool desc = ((e & ksz) == 0);
          if (desc ? !before : before) { sv[e] = v1; sv[p] = v0; si[e] = i1; si[p] = i0; }
        }
      }
    }
  }
  __syncthreads();
  if (t < K_TOP) {
    double v = sv[t];
    topIdx[(size_t)row * K_TOP + t] = si[t];
    topVal[(size_t)row * K_TOP + t] = (float)(v > 0.0 ? v : 0.0);   // relu
  }
}

// ---------------- K8: zero output row + scatter ----------------
__global__ __launch_bounds__(256) void write_out(const int* __restrict__ topIdx,
                                                 const float* __restrict__ topVal,
                                                 float* __restrict__ out) {
  int row = blockIdx.x, t = threadIdx.x;
  float4* o = (float4*)(out + (size_t)row * D_SAE);
  float4 z = {0.f, 0.f, 0.f, 0.f};
  for (int i = t; i < D_SAE / 4; i += 256) o[i] = z;
  __syncthreads();
  if (t < K_TOP) {
    int idx = topIdx[(size_t)row * K_TOP + t];
    if ((unsigned)idx < (unsigned)D_SAE)
      out[(size_t)row * D_SAE + idx] = topVal[(size_t)row * K_TOP + t];
  }
}

extern "C" void kernel_launch(void* const* d_in, const int* in_sizes, int n_in,
                              void* d_out, int out_size, void* d_ws, size_t ws_size,
                              hipStream_t stream) {
  const float* x     = (const float*)d_in[0];
  const float* W     = (const float*)d_in[1];
  const float* b_enc = (const float*)d_in[2];
  const float* b_dec = (const float*)d_in[3];
  // d_in[4] = k (==64, fixed by setup_inputs) -> compile-time K_TOP

  // big scratch carved out of d_out (1 GiB), lifetime-disjoint:
  char* ob = (char*)d_out;
  unsigned short* pre  = (unsigned short*)ob;                        // [0, 512Mi) approx pre bf16
  unsigned short* Wt   = (unsigned short*)(ob + (size_t)536870912);  // [512Mi, 768Mi) W^T bf16
  float* xc            = (float*)(ob + (size_t)805306368);           // [768Mi+37Mi...) x-b_dec fp32
  unsigned short* x_bf = (unsigned short*)(ob + (size_t)838860800);  // 16 MiB bf16 x

  char* wsb = (char*)d_ws;                                           // ~43 MiB used
  int*    cand_idx = (int*)wsb;                                      // 8 MiB
  double* candVal  = (double*)(wsb + ((size_t)8 << 20));             // 16 MiB
  unsigned long long* pairs = (unsigned long long*)(wsb + ((size_t)24 << 20)); // 16 MiB
  int* cand_cnt = (int*)(wsb + ((size_t)40 << 20));                  // 16 KiB
  int* tileCnt  = (int*)(wsb + ((size_t)40 << 20) + 65536);
  int* tileOff  = tileCnt + NTILE;
  int* cursor   = tileOff + NTILE;
  int* topIdx   = (int*)(wsb + ((size_t)41 << 20));                  // 1 MiB
  float* topVal = (float*)(wsb + ((size_t)42 << 20));                // 1 MiB

  prep_x<<<8192, 256, 0, stream>>>(x, b_dec, x_bf, xc);
  transpose_w<<<dim3(1024, 32), 256, 0, stream>>>(W, Wt);
  gemm_bf16_8ph<<<dim3(4096), 512, 0, stream>>>(x_bf, Wt, b_enc, pre);
  select_cands<<<B_ROWS, 256, 0, stream>>>(pre, cand_idx, cand_cnt);
  zero_counts<<<2, 256, 0, stream>>>(tileCnt, cursor);
  count_pairs<<<B_ROWS, 256, 0, stream>>>(cand_idx, cand_cnt, tileCnt);
  scan_tiles<<<1, 64, 0, stream>>>(tileCnt, tileOff);
  scatter_pairs<<<B_ROWS, 256, 0, stream>>>(cand_idx, cand_cnt, tileOff, cursor, pairs);
  recompute_exact<<<NTILE, 256, 0, stream>>>(W, xc, b_enc, pairs, tileCnt, tileOff, candVal);
  topk_select<<<B_ROWS, 256, 0, stream>>>(cand_idx, cand_cnt, candVal, topIdx, topVal);
  write_out<<<B_ROWS, 256, 0, stream>>>(topIdx, topVal, (float*)d_out);
}

// Round 2
// 4587.524 us; speedup vs baseline: 1.0400x; 1.0400x over previous
//
#include <hip/hip_runtime.h>
#include <hip/hip_bf16.h>

// BatchTopKSAE: pre = relu((x - b_dec) @ W_enc + b_enc); per-row top-64 scatter.
// B=4096, D_IN=2048, D_SAE=65536, k=64 (k input is fixed by setup_inputs).
//
// Pipeline:
//  K1 prep_x      : xc = x - b_dec (fp32), x_bf = bf16(xc)
//  K2 transpose_w : Wt[n][k] = bf16(W[k][n])   (GEMM wants B^T = [N][K])
//  K3 gemm_bf16_8ph: pre[m][n] = relu(x_bf . Wt^T + b_enc)
//     256x256 tile, BK=64, 8 waves, faithful m201 8-phase schedule:
//     BLOCK-level Gray quadrants (all waves same 128x128 C-quadrant per phase,
//     wave sub-tile 64x32), 1 half-tile staged per phase at its race-free slot,
//     counted vmcnt(4) at ph4/ph8 only, ds_reads issued BEFORE the mid-barrier.
//  K4 select_cands: per row, histogram -> threshold; collect candidate cols (~140)
//  K5 bucket      : group (row,col,slot) pairs by 128-col tile of W
//  K6 recompute   : exact fp64 dot for every candidate (W read coalesced, LDS panel)
//  K7 topk_select : per-row bitonic sort of <=512 candidates on exact value, keep 64
//  K8 write_out   : zero row + scatter 64 exact values

#define D_IN   2048
#define D_SAE  65536
#define B_ROWS 4096
#define K_TOP  64
#define MAXC   512
#define NTILE  512   // D_SAE / 128

using bf16x8  = __attribute__((ext_vector_type(8))) __bf16;
using floatx4 = __attribute__((ext_vector_type(4))) float;

__device__ __forceinline__ unsigned short f2bf_rne(float f) {
  union { float f; unsigned u; } x; x.f = f;
  unsigned r = x.u + 0x7FFFu + ((x.u >> 16) & 1u);
  return (unsigned short)(r >> 16);
}

__device__ __forceinline__ void async_load16(const void* g, void* l) {
  __builtin_amdgcn_global_load_lds((const __attribute__((address_space(1))) void*)g,
                                   (__attribute__((address_space(3))) void*)l, 16, 0, 0);
}

// ---------------- K1: x - b_dec -> fp32 + bf16 ----------------
__global__ __launch_bounds__(256) void prep_x(const float* __restrict__ x,
                                              const float* __restrict__ b_dec,
                                              unsigned short* __restrict__ x_bf,
                                              float* __restrict__ xc) {
  int i4 = blockIdx.x * 256 + threadIdx.x;          // 2,097,152 float4s
  const float4* xv = (const float4*)x;
  float4 v = xv[i4];
  int kb = (i4 * 4) & (D_IN - 1);
  v.x -= b_dec[kb + 0]; v.y -= b_dec[kb + 1]; v.z -= b_dec[kb + 2]; v.w -= b_dec[kb + 3];
  ((float4*)xc)[i4] = v;
  ushort4 b;
  b.x = f2bf_rne(v.x); b.y = f2bf_rne(v.y); b.z = f2bf_rne(v.z); b.w = f2bf_rne(v.w);
  ((ushort4*)x_bf)[i4] = b;
}

// ---------------- K2: W[k][n] -> Wt[n][k] bf16 ----------------
__global__ __launch_bounds__(256) void transpose_w(const float* __restrict__ W,
                                                   unsigned short* __restrict__ Wt) {
  __shared__ float tile[64][65];
  int bn = blockIdx.x, bk = blockIdx.y;
  int t = threadIdx.x;
  int c = t & 63, r0 = t >> 6;
#pragma unroll
  for (int i = 0; i < 16; i++) {
    int r = r0 + i * 4;
    tile[r][c] = W[(size_t)(bk * 64 + r) * D_SAE + bn * 64 + c];
  }
  __syncthreads();
#pragma unroll
  for (int i = 0; i < 16; i++) {
    int r = r0 + i * 4;
    Wt[(size_t)(bn * 64 + r) * D_IN + bk * 64 + c] = f2bf_rne(tile[c][r]);
  }
}

// ---------------- K3: bf16 MFMA GEMM, 256^2 8-phase (m201-faithful) ----------------
// C[4096][65536] = A[M][K] * Bt[N][K]^T, tile 256x256, BK=64, 512 thr = 8 waves.
// LDS 128 KiB: A: [buf0 32K][buf1 32K] @0; B: same @64K. Even tiles in buf0, odd buf1.
// Half-tile = 128 rows x 64 cols bf16 (16 KiB): A0=rows 0-127, A1=128-255; B likewise.
//
// Per phase (block-quadrant Q(Qm,Qn), Gray order (0,0)(0,1)(1,1)(1,0) per tile):
//   ds_read changed-half frags (4/8/12 x b128, issued BEFORE barrier)
//   issue 1 half-tile stage (2 x global_load_lds / thread)
//   [vmcnt(4) at ph4/ph8 only — 2 half-tiles stay in flight, never drain mid-loop]
//   s_barrier ; lgkmcnt(0) ; setprio(1) 16 MFMA setprio(0) ; s_barrier
//
// Stage slots (race-free ledger; half H(t) staged only after last phase reading H):
//   ph1:A1(t+1) ph2:B0(t+1) ph3:A0(t+2) ph4:B1(t+2)
//   ph5:A1(t+2) ph6:B0(t+2) ph7:A0(t+3) ph8:B1(t+3)
// In-flight invariant at iteration entry: [A0(t+1), B1(t+1)] (4 loads).
#define GNT (D_IN / 64)   // 32 K-tiles

#define STAGE_A(kt, h, bf) do { \
    const unsigned short* s_ = A + aRow + (size_t)(h) * 128 * D_IN + (size_t)(kt) * 64; \
    unsigned char* d_ = lds + (bf) * 32768 + (h) * 16384 + t * 16; \
    async_load16(s_, d_); async_load16(s_ + 64 * D_IN, d_ + 8192); \
  } while (0)
#define STAGE_B(kt, h, bf) do { \
    const unsigned short* s_ = Bt + bRow + (size_t)(h) * 128 * D_IN + (size_t)(kt) * 64; \
    unsigned char* d_ = lds + 65536 + (bf) * 32768 + (h) * 16384 + t * 16; \
    async_load16(s_, d_); async_load16(s_ + 64 * D_IN, d_ + 8192); \
  } while (0)
#define LOAD_A(bf, Qm) do { _Pragma("unroll") for (int i_ = 0; i_ < 4; ++i_) { \
    int o_ = (bf) * 32768 + aOffW + (Qm) * 16384 + i_ * 2048; \
    aF[i_][0] = *(const bf16x8*)(lds + o_); \
    aF[i_][1] = *(const bf16x8*)(lds + (o_ ^ 64)); } } while (0)
#define LOAD_B(bf, Qn) do { _Pragma("unroll") for (int j_ = 0; j_ < 2; ++j_) { \
    int o_ = 65536 + (bf) * 32768 + bOffW + (Qn) * 16384 + j_ * 2048; \
    bF[j_][0] = *(const bf16x8*)(lds + o_); \
    bF[j_][1] = *(const bf16x8*)(lds + (o_ ^ 64)); } } while (0)
#define MFMA_Q(QM, QN) do { \
    __builtin_amdgcn_s_setprio(1); \
    _Pragma("unroll") for (int i_ = 0; i_ < 4; ++i_) \
    _Pragma("unroll") for (int j_ = 0; j_ < 2; ++j_) { \
      acc[QM][QN][i_][j_] = __builtin_amdgcn_mfma_f32_16x16x32_bf16( \
          aF[i_][0], bF[j_][0], acc[QM][QN][i_][j_], 0, 0, 0); \
      acc[QM][QN][i_][j_] = __builtin_amdgcn_mfma_f32_16x16x32_bf16( \
          aF[i_][1], bF[j_][1], acc[QM][QN][i_][j_], 0, 0, 0); \
    } \
    __builtin_amdgcn_s_setprio(0); \
  } while (0)
#define BARRIER() asm volatile("s_barrier" ::: "memory")
#define WAIT_LGKM0() do { asm volatile("s_waitcnt lgkmcnt(0)" ::: "memory"); \
    __builtin_amdgcn_sched_barrier(0); } while (0)
#define WAIT_VM(n) asm volatile("s_waitcnt vmcnt(" #n ")" ::: "memory")

__global__ __launch_bounds__(512, 2) void gemm_bf16_8ph(
    const unsigned short* __restrict__ A,
    const unsigned short* __restrict__ Bt,
    const float* __restrict__ b_enc,
    unsigned short* __restrict__ pre) {
  __shared__ __align__(16) unsigned char lds[131072];

  const int t = threadIdx.x;
  // T1: bijective XCD swizzle (4096 blocks % 8 == 0), m-block fastest: each XCD's
  // resident blocks sweep the 16 m-blocks of consecutive N-panels -> B L2-local.
  const int orig = blockIdx.x;
  const int swz = (orig & 7) * 512 + (orig >> 3);
  const int mBase = (swz & 15) << 8;   // 16 m-blocks
  const int nBase = (swz >> 4) << 8;   // 256 n-blocks

  const int lane = t & 63, wave = t >> 6;
  const int wm = wave >> 2, wn = wave & 3;      // 2 x 4 waves; 64x32 sub-tile per quadrant
  const int frow = lane & 15, khalf = lane >> 4;

  // staging map: half-tile = 128 rows x 8 16B-chunks; thread t covers rows t>>3 and
  // t>>3 + 64 at chunk t&7, LDS dest lane-linear (global_load_lds requirement).
  const int r0 = t >> 3, q0 = t & 7;
  const int kc0 = q0 ^ (r0 & 7);                // inverse T2 swizzle on global source
  const size_t aRow = (size_t)(mBase + r0) * D_IN + kc0 * 8;
  const size_t bRow = (size_t)(nBase + r0) * D_IN + kc0 * 8;

  // ds_read T2 swizzle: byte(row, chunk g) = row*128 + (g*16 ^ ((row&7)<<4));
  // row & 7 == frow & 7 for all fragment rows. ks=1 chunk is (byte ^ 64).
  const int qswz = (khalf << 4) ^ ((frow & 7) << 4);
  const int aOffW = (wm * 64 + frow) * 128 + qswz;
  const int bOffW = (wn * 32 + frow) * 128 + qswz;

  floatx4 acc[2][2][4][2];
#pragma unroll
  for (int qm = 0; qm < 2; ++qm)
#pragma unroll
    for (int qn = 0; qn < 2; ++qn)
#pragma unroll
      for (int i = 0; i < 4; ++i)
#pragma unroll
        for (int j = 0; j < 2; ++j) acc[qm][qn][i][j] = (floatx4){0.f, 0.f, 0.f, 0.f};
  bf16x8 aF[4][2], bF[2][2];

  // prologue: tile 0 fully into buf0; A0(1), B1(1) into buf1 -> in-flight order
  // [A0(1), B1(1)] after vmcnt(4), matching the loop invariant.
  STAGE_A(0, 0, 0); STAGE_A(0, 1, 0); STAGE_B(0, 0, 0); STAGE_B(0, 1, 0);
  STAGE_A(1, 0, 1); STAGE_B(1, 1, 1);
  WAIT_VM(4);
  BARRIER();

#pragma unroll 1
  for (int it = 0; it < GNT / 2 - 1; ++it) {      // 15 steady iterations (tiles 0..29)
    const int t0 = it * 2;                        // even tile -> buf0, odd -> buf1
    // ph1: Q(0,0) of tile t0
    LOAD_A(0, 0); LOAD_B(0, 0);
    STAGE_A(t0 + 1, 1, 1);
    BARRIER(); WAIT_LGKM0(); MFMA_Q(0, 0); BARRIER();
    // ph2: Q(0,1)
    LOAD_B(0, 1);
    STAGE_B(t0 + 1, 0, 1);
    BARRIER(); WAIT_LGKM0(); MFMA_Q(0, 1); BARRIER();
    // ph3: Q(1,1)
    LOAD_A(0, 1);
    STAGE_A(t0 + 2, 0, 0);
    BARRIER(); WAIT_LGKM0(); MFMA_Q(1, 1); BARRIER();
    // ph4: Q(1,0) — counted wait: retire tile t0+1's 4 half-tiles, leave 2 in flight
    LOAD_B(0, 0);
    STAGE_B(t0 + 2, 1, 0);
    WAIT_VM(4);
    BARRIER(); WAIT_LGKM0(); MFMA_Q(1, 0); BARRIER();
    // ph5: Q(0,0) of tile t0+1 (buf1)
    LOAD_A(1, 0); LOAD_B(1, 0);
    STAGE_A(t0 + 2, 1, 0);
    BARRIER(); WAIT_LGKM0(); MFMA_Q(0, 0); BARRIER();
    // ph6: Q(0,1)
    LOAD_B(1, 1);
    STAGE_B(t0 + 2, 0, 0);
    BARRIER(); WAIT_LGKM0(); MFMA_Q(0, 1); BARRIER();
    // ph7: Q(1,1)
    LOAD_A(1, 1);
    STAGE_A(t0 + 3, 0, 1);
    BARRIER(); WAIT_LGKM0(); MFMA_Q(1, 1); BARRIER();
    // ph8: Q(1,0) — counted wait: retire tile t0+2, leave [A0(t0+3), B1(t0+3)]
    LOAD_B(1, 0);
    STAGE_B(t0 + 3, 1, 1);
    WAIT_VM(4);
    BARRIER(); WAIT_LGKM0(); MFMA_Q(1, 0); BARRIER();
  }

  // peeled final pair (tiles 30, 31): finish staging tile 31, single vmcnt(0) drain
  LOAD_A(0, 0); LOAD_B(0, 0);
  STAGE_A(GNT - 1, 1, 1);
  BARRIER(); WAIT_LGKM0(); MFMA_Q(0, 0); BARRIER();
  LOAD_B(0, 1);
  STAGE_B(GNT - 1, 0, 1);
  BARRIER(); WAIT_LGKM0(); MFMA_Q(0, 1); BARRIER();
  LOAD_A(0, 1);
  BARRIER(); WAIT_LGKM0(); MFMA_Q(1, 1); BARRIER();
  LOAD_B(0, 0);
  WAIT_VM(0);
  BARRIER(); WAIT_LGKM0(); MFMA_Q(1, 0); BARRIER();
  LOAD_A(1, 0); LOAD_B(1, 0);
  BARRIER(); WAIT_LGKM0(); MFMA_Q(0, 0); BARRIER();
  LOAD_B(1, 1);
  BARRIER(); WAIT_LGKM0(); MFMA_Q(0, 1); BARRIER();
  LOAD_A(1, 1);
  BARRIER(); WAIT_LGKM0(); MFMA_Q(1, 1); BARRIER();
  LOAD_B(1, 0);
  WAIT_LGKM0(); MFMA_Q(1, 0);

  // epilogue: C/D map col=lane&15, row=(lane>>4)*4+reg (m89-verified)
  const int ccol = lane & 15, crow = (lane >> 4) * 4;
#pragma unroll
  for (int Qn = 0; Qn < 2; ++Qn)
#pragma unroll
    for (int j = 0; j < 2; ++j) {
      int n = nBase + Qn * 128 + wn * 32 + j * 16 + ccol;
      float be = b_enc[n];
#pragma unroll
      for (int Qm = 0; Qm < 2; ++Qm)
#pragma unroll
        for (int i = 0; i < 4; ++i)
#pragma unroll
          for (int v = 0; v < 4; ++v) {
            int m = mBase + Qm * 128 + wm * 64 + i * 16 + crow + v;
            float val = acc[Qm][Qn][i][j][v] + be;
            val = val > 0.f ? val : 0.f;                 // relu
            pre[(size_t)m * D_SAE + n] = f2bf_rne(val);
          }
    }
}

#undef STAGE_A
#undef STAGE_B
#undef LOAD_A
#undef LOAD_B
#undef MFMA_Q

// ---------------- K4: per-row candidate selection ----------------
__global__ __launch_bounds__(256) void select_cands(const unsigned short* __restrict__ pre,
                                                    int* __restrict__ cand_idx,
                                                    int* __restrict__ cand_cnt) {
  __shared__ int hist[64];
  __shared__ float sT;
  __shared__ int scnt;
  int row = blockIdx.x, t = threadIdx.x;
  for (int i = t; i < 64; i += 256) hist[i] = 0;
  if (t == 0) scnt = 0;
  __syncthreads();
  const uint4* p = (const uint4*)(pre + (size_t)row * D_SAE);   // 8192 x 16B
  for (int i = t; i < 8192; i += 256) {
    uint4 w = p[i];
    unsigned wd[4] = {w.x, w.y, w.z, w.w};
#pragma unroll
    for (int e = 0; e < 4; e++) {
      unsigned lo = wd[e] << 16, hi = wd[e] & 0xFFFF0000u;
      float f0 = __uint_as_float(lo), f1 = __uint_as_float(hi);
      if (f0 >= 0.5f) atomicAdd(&hist[min((int)(lo >> 20) - 1008, 63)], 1);
      if (f1 >= 0.5f) atomicAdd(&hist[min((int)(hi >> 20) - 1008, 63)], 1);
    }
  }
  __syncthreads();
  if (t == 0) {
    int cum = 0, b = 63;
    for (; b >= 0; b--) { cum += hist[b]; if (cum >= K_TOP) break; }
    if (b < 0) b = 0;
    // bin floor minus margin: covers bf16-GEMM (~0.03 max) + bf16-store error
    sT = __uint_as_float((unsigned)(b + 1008) << 20) - 0.09f;
  }
  __syncthreads();
  float T = sT;
  for (int i = t; i < 8192; i += 256) {
    uint4 w = p[i];
    unsigned wd[4] = {w.x, w.y, w.z, w.w};
#pragma unroll
    for (int e = 0; e < 4; e++) {
      unsigned lo = wd[e] << 16, hi = wd[e] & 0xFFFF0000u;
      float f0 = __uint_as_float(lo), f1 = __uint_as_float(hi);
      if (f0 >= T) { int q = atomicAdd(&scnt, 1); if (q < MAXC) cand_idx[(size_t)row * MAXC + q] = i * 8 + e * 2; }
      if (f1 >= T) { int q = atomicAdd(&scnt, 1); if (q < MAXC) cand_idx[(size_t)row * MAXC + q] = i * 8 + e * 2 + 1; }
    }
  }
  __syncthreads();
  if (t == 0) cand_cnt[row] = min(scnt, MAXC);
}

// ---------------- K5: bucket candidates by 128-col tile ----------------
__global__ void zero_counts(int* tileCnt, int* cursor) {
  int i = blockIdx.x * 256 + threadIdx.x;
  if (i < NTILE) { tileCnt[i] = 0; cursor[i] = 0; }
}
__global__ __launch_bounds__(256) void count_pairs(const int* __restrict__ cand_idx,
                                                   const int* __restrict__ cand_cnt,
                                                   int* __restrict__ tileCnt) {
  int row = blockIdx.x, cnt = cand_cnt[row];
  for (int s = threadIdx.x; s < cnt; s += 256)
    atomicAdd(&tileCnt[cand_idx[(size_t)row * MAXC + s] >> 7], 1);
}
__global__ void scan_tiles(const int* __restrict__ tileCnt, int* __restrict__ tileOff) {
  if (threadIdx.x == 0) {
    int acc = 0;
    for (int i = 0; i < NTILE; i++) { tileOff[i] = acc; acc += tileCnt[i]; }
  }
}
__global__ __launch_bounds__(256) void scatter_pairs(const int* __restrict__ cand_idx,
                                                     const int* __restrict__ cand_cnt,
                                                     const int* __restrict__ tileOff,
                                                     int* __restrict__ cursor,
                                                     unsigned long long* __restrict__ pairs) {
  int row = blockIdx.x, cnt = cand_cnt[row];
  for (int s = threadIdx.x; s < cnt; s += 256) {
    int col = cand_idx[(size_t)row * MAXC + s];
    int tl = col >> 7;
    int q = atomicAdd(&cursor[tl], 1);
    pairs[tileOff[tl] + q] =
        ((unsigned long long)row << 32) | ((unsigned long long)(unsigned)col << 16) | (unsigned)s;
  }
}

// ---------------- K6: exact fp64 recompute of candidates ----------------
__global__ __launch_bounds__(256) void recompute_exact(const float* __restrict__ W,
                                                       const float* __restrict__ xc,
                                                       const float* __restrict__ b_enc,
                                                       const unsigned long long* __restrict__ pairs,
                                                       const int* __restrict__ tileCnt,
                                                       const int* __restrict__ tileOff,
                                                       double* __restrict__ candVal) {
  __shared__ float Wl[512 * 17];     // 512 k x 16 cols, pad 17 (bank-conflict free)
  __shared__ int lists[8][256];
  __shared__ int lcnt[8];
  __shared__ double pacc[256];
  int tile = blockIdx.x, t = threadIdx.x;
  int n0 = tile << 7;
  int nP = tileCnt[tile], base = tileOff[tile];
  if (t < 8) lcnt[t] = 0;
  __syncthreads();
  for (int i = t; i < nP; i += 256) {
    int col = (int)((pairs[base + i] >> 16) & 0xFFFF);
    int st = (col >> 4) & 7;
    int q = atomicAdd(&lcnt[st], 1);
    if (q < 256) lists[st][q] = i;
  }
  int lane = t & 63, wave = t >> 6;
  for (int st = 0; st < 8; st++) {
    __syncthreads();
    int cnt = min(lcnt[st], 256);
    for (int i = t; i < cnt; i += 256) pacc[i] = 0.0;
    for (int kc = 0; kc < 4; kc++) {
      __syncthreads();
      for (int e = t; e < 512 * 16; e += 256) {
        int k = e >> 4, c = e & 15;
        Wl[k * 17 + c] = W[(size_t)(kc * 512 + k) * D_SAE + n0 + st * 16 + c];
      }
      __syncthreads();
      for (int pi = wave; pi < cnt; pi += 4) {
        unsigned long long u = pairs[base + lists[st][pi]];
        int row = (int)(u >> 32);
        int cc = (int)((u >> 16) & 15);
        const float* xr = xc + (size_t)row * D_IN + kc * 512;
        double a = 0.0;
#pragma unroll
        for (int j = 0; j < 8; j++) {
          int k = lane + j * 64;
          a += (double)xr[k] * (double)Wl[k * 17 + cc];
        }
#pragma unroll
        for (int off = 32; off > 0; off >>= 1) a += __shfl_down(a, off, 64);
        if (lane == 0) pacc[pi] += a;
      }
    }
    __syncthreads();
    for (int i = t; i < cnt; i += 256) {
      unsigned long long u = pairs[base + lists[st][i]];
      int row = (int)(u >> 32);
      int col = (int)((u >> 16) & 0xFFFF);
      int slot = (int)(u & 0xFFFF);
      candVal[(size_t)row * MAXC + slot] = pacc[i] + (double)b_enc[col];
    }
  }
}

// ---------------- K7: per-row bitonic top-64 on exact values ----------------
__global__ __launch_bounds__(256) void topk_select(const int* __restrict__ cand_idx,
                                                   const int* __restrict__ cand_cnt,
                                                   const double* __restrict__ candVal,
                                                   int* __restrict__ topIdx,
                                                   float* __restrict__ topVal) {
  __shared__ double sv[MAXC];
  __shared__ int si[MAXC];
  int row = blockIdx.x, t = threadIdx.x;
  int cnt = cand_cnt[row];
  for (int i = t; i < MAXC; i += 256) {
    if (i < cnt) { sv[i] = candVal[(size_t)row * MAXC + i]; si[i] = cand_idx[(size_t)row * MAXC + i]; }
    else         { sv[i] = -1.0e300; si[i] = 0x7FFFFFFF; }
  }
  for (int ksz = 2; ksz <= MAXC; ksz <<= 1) {
    for (int j = ksz >> 1; j > 0; j >>= 1) {
      __syncthreads();
      for (int e = t; e < MAXC; e += 256) {
        int p = e ^ j;
        if (p > e) {
          double v0 = sv[e], v1 = sv[p];
          int i0 = si[e], i1 = si[p];
          bool before = (v0 > v1) || (v0 == v1 && i0 < i1);   // e precedes p in desc order
          bool desc = ((e & ksz) == 0);
          if (desc ? !before : before) { sv[e] = v1; sv[p] = v0; si[e] = i1; si[p] = i0; }
        }
      }
    }
  }
  __syncthreads();
  if (t < K_TOP) {
    double v = sv[t];
    topIdx[(size_t)row * K_TOP + t] = si[t];
    topVal[(size_t)row * K_TOP + t] = (float)(v > 0.0 ? v : 0.0);   // relu
  }
}

// ---------------- K8: zero output row + scatter ----------------
__global__ __launch_bounds__(256) void write_out(const int* __restrict__ topIdx,
                                                 const float* __restrict__ topVal,
                                                 float* __restrict__ out) {
  int row = blockIdx.x, t = threadIdx.x;
  float4* o = (float4*)(out + (size_t)row * D_SAE);
  float4 z = {0.f, 0.f, 0.f, 0.f};
  for (int i = t; i < D_SAE / 4; i += 256) o[i] = z;
  __syncthreads();
  if (t < K_TOP) {
    int idx = topIdx[(size_t)row * K_TOP + t];
    if ((unsigned)idx < (unsigned)D_SAE)
      out[(size_t)row * D_SAE + idx] = topVal[(size_t)row * K_TOP + t];
  }
}

extern "C" void kernel_launch(void* const* d_in, const int* in_sizes, int n_in,
                              void* d_out, int out_size, void* d_ws, size_t ws_size,
                              hipStream_t stream) {
  const float* x     = (const float*)d_in[0];
  const float* W     = (const float*)d_in[1];
  const float* b_enc = (const float*)d_in[2];
  const float* b_dec = (const float*)d_in[3];
  // d_in[4] = k (==64, fixed by setup_inputs) -> compile-time K_TOP

  // big scratch carved out of d_out (1 GiB), lifetime-disjoint:
  char* ob = (char*)d_out;
  unsigned short* pre  = (unsigned short*)ob;                        // [0, 512Mi) approx pre bf16
  unsigned short* Wt   = (unsigned short*)(ob + (size_t)536870912);  // [512Mi, 768Mi) W^T bf16
  float* xc            = (float*)(ob + (size_t)805306368);           // [768Mi+37Mi...) x-b_dec fp32
  unsigned short* x_bf = (unsigned short*)(ob + (size_t)838860800);  // 16 MiB bf16 x

  char* wsb = (char*)d_ws;                                           // ~43 MiB used
  int*    cand_idx = (int*)wsb;                                      // 8 MiB
  double* candVal  = (double*)(wsb + ((size_t)8 << 20));             // 16 MiB
  unsigned long long* pairs = (unsigned long long*)(wsb + ((size_t)24 << 20)); // 16 MiB
  int* cand_cnt = (int*)(wsb + ((size_t)40 << 20));                  // 16 KiB
  int* tileCnt  = (int*)(wsb + ((size_t)40 << 20) + 65536);
  int* tileOff  = tileCnt + NTILE;
  int* cursor   = tileOff + NTILE;
  int* topIdx   = (int*)(wsb + ((size_t)41 << 20));                  // 1 MiB
  float* topVal = (float*)(wsb + ((size_t)42 << 20));                // 1 MiB

  prep_x<<<8192, 256, 0, stream>>>(x, b_dec, x_bf, xc);
  transpose_w<<<dim3(1024, 32), 256, 0, stream>>>(W, Wt);
  gemm_bf16_8ph<<<dim3(4096), 512, 0, stream>>>(x_bf, Wt, b_enc, pre);
  select_cands<<<B_ROWS, 256, 0, stream>>>(pre, cand_idx, cand_cnt);
  zero_counts<<<2, 256, 0, stream>>>(tileCnt, cursor);
  count_pairs<<<B_ROWS, 256, 0, stream>>>(cand_idx, cand_cnt, tileCnt);
  scan_tiles<<<1, 64, 0, stream>>>(tileCnt, tileOff);
  scatter_pairs<<<B_ROWS, 256, 0, stream>>>(cand_idx, cand_cnt, tileOff, cursor, pairs);
  recompute_exact<<<NTILE, 256, 0, stream>>>(W, xc, b_enc, pairs, tileCnt, tileOff, candVal);
  topk_select<<<B_ROWS, 256, 0, stream>>>(cand_idx, cand_cnt, candVal, topIdx, topVal);
  write_out<<<B_ROWS, 256, 0, stream>>>(topIdx, topVal, (float*)d_out);
}

// Round 3
// 4567.197 us; speedup vs baseline: 1.0447x; 1.0045x over previous
//
#include <hip/hip_runtime.h>
#include <hip/hip_bf16.h>

// BatchTopKSAE: pre = relu((x - b_dec) @ W_enc + b_enc); per-row top-64 scatter.
// B=4096, D_IN=2048, D_SAE=65536, k=64 (k input is fixed by setup_inputs).
//
// Pipeline:
//  K1 prep_x      : xc = x - b_dec (fp32), x_bf = bf16(xc)
//  K2 transpose_w : Wt[n][k] = bf16(W[k][n])   (GEMM wants B^T = [N][K])
//  K3 gemm_bf16_8ph (x2 launches, N-halves for rocprof visibility):
//     256x256 tile, BK=64, 8 waves, m201 8-phase block-quadrant schedule,
//     dual B-register sets (each LDS half ds_read exactly once per K-tile).
//  K4 select_cands: single pass; prefilter >=2.0 into LDS buffer + histogram;
//     threshold from hist; filter buffer (fallback full re-scan if degenerate)
//  K5 bucket      : group (row,col,slot) pairs by 128-col tile of W
//  K6 recompute   : exact fp64 dot for every candidate (W read coalesced, LDS panel)
//  K7 topk_select : per-row bitonic sort of <=512 candidates on exact value, keep 64
//  K8 write_out   : zero row + scatter 64 exact values

#define D_IN   2048
#define D_SAE  65536
#define B_ROWS 4096
#define K_TOP  64
#define MAXC   512
#define NTILE  512   // D_SAE / 128
#define PREF   2048  // K4 prefilter buffer entries

using bf16x8  = __attribute__((ext_vector_type(8))) __bf16;
using floatx4 = __attribute__((ext_vector_type(4))) float;

__device__ __forceinline__ unsigned short f2bf_rne(float f) {
  union { float f; unsigned u; } x; x.f = f;
  unsigned r = x.u + 0x7FFFu + ((x.u >> 16) & 1u);
  return (unsigned short)(r >> 16);
}

__device__ __forceinline__ void async_load16(const void* g, void* l) {
  __builtin_amdgcn_global_load_lds((const __attribute__((address_space(1))) void*)g,
                                   (__attribute__((address_space(3))) void*)l, 16, 0, 0);
}

// ---------------- K1: x - b_dec -> fp32 + bf16 ----------------
__global__ __launch_bounds__(256) void prep_x(const float* __restrict__ x,
                                              const float* __restrict__ b_dec,
                                              unsigned short* __restrict__ x_bf,
                                              float* __restrict__ xc) {
  int i4 = blockIdx.x * 256 + threadIdx.x;          // 2,097,152 float4s
  const float4* xv = (const float4*)x;
  float4 v = xv[i4];
  int kb = (i4 * 4) & (D_IN - 1);
  v.x -= b_dec[kb + 0]; v.y -= b_dec[kb + 1]; v.z -= b_dec[kb + 2]; v.w -= b_dec[kb + 3];
  ((float4*)xc)[i4] = v;
  ushort4 b;
  b.x = f2bf_rne(v.x); b.y = f2bf_rne(v.y); b.z = f2bf_rne(v.z); b.w = f2bf_rne(v.w);
  ((ushort4*)x_bf)[i4] = b;
}

// ---------------- K2: W[k][n] -> Wt[n][k] bf16 ----------------
__global__ __launch_bounds__(256) void transpose_w(const float* __restrict__ W,
                                                   unsigned short* __restrict__ Wt) {
  __shared__ float tile[64][65];
  int bn = blockIdx.x, bk = blockIdx.y;
  int t = threadIdx.x;
  int c = t & 63, r0 = t >> 6;
#pragma unroll
  for (int i = 0; i < 16; i++) {
    int r = r0 + i * 4;
    tile[r][c] = W[(size_t)(bk * 64 + r) * D_SAE + bn * 64 + c];
  }
  __syncthreads();
#pragma unroll
  for (int i = 0; i < 16; i++) {
    int r = r0 + i * 4;
    Wt[(size_t)(bn * 64 + r) * D_IN + bk * 64 + c] = f2bf_rne(tile[c][r]);
  }
}

// ---------------- K3: bf16 MFMA GEMM, 256^2 8-phase ----------------
// C[4096][65536] = A[M][K] * Bt[N][K]^T, tile 256x256, BK=64, 512 thr = 8 waves.
// LDS 128 KiB: A: [buf0 32K][buf1 32K] @0; B same @64K. Even tiles buf0, odd buf1.
// Half-tile = 128 rows x 64 cols bf16 (16 KiB).
//
// Per tile, 4 phases over block quadrants (0,0)(0,1)(1,1)(1,0); dual bF register
// sets let each LDS half be read exactly ONCE per tile (reads: 12/4/8/0 b128).
// Stage slots (race-free; half H(t) staged only after last phase reading H):
//   ph1:A1(t+1) ph2:B0(t+1) ph3:A0(t+2) ph4:B1(t+2)
//   ph5:A1(t+2) ph6:B0(t+2) ph7:A0(t+3) ph8:B1(t+3)
// vmcnt(4) at ph4/ph8 only (2 half-tiles always in flight, no mid-loop drain).
#define GNT (D_IN / 64)   // 32 K-tiles

#define STAGE_A(kt, h, bf) do { \
    const unsigned short* s_ = A + aRow + (size_t)(h) * 128 * D_IN + (size_t)(kt) * 64; \
    unsigned char* d_ = lds + (bf) * 32768 + (h) * 16384 + t * 16; \
    async_load16(s_, d_); async_load16(s_ + 64 * D_IN, d_ + 8192); \
  } while (0)
#define STAGE_B(kt, h, bf) do { \
    const unsigned short* s_ = Bt + bRow + (size_t)(h) * 128 * D_IN + (size_t)(kt) * 64; \
    unsigned char* d_ = lds + 65536 + (bf) * 32768 + (h) * 16384 + t * 16; \
    async_load16(s_, d_); async_load16(s_ + 64 * D_IN, d_ + 8192); \
  } while (0)
#define LOAD_A(bf, Qm) do { _Pragma("unroll") for (int i_ = 0; i_ < 4; ++i_) { \
    int o_ = (bf) * 32768 + aOffW + (Qm) * 16384 + i_ * 2048; \
    aF[i_][0] = *(const bf16x8*)(lds + o_); \
    aF[i_][1] = *(const bf16x8*)(lds + (o_ ^ 64)); } } while (0)
#define LOAD_B(bf, Qn, SET) do { _Pragma("unroll") for (int j_ = 0; j_ < 2; ++j_) { \
    int o_ = 65536 + (bf) * 32768 + bOffW + (Qn) * 16384 + j_ * 2048; \
    bF[SET][j_][0] = *(const bf16x8*)(lds + o_); \
    bF[SET][j_][1] = *(const bf16x8*)(lds + (o_ ^ 64)); } } while (0)
#define MFMA_Q(QM, QN, SET) do { \
    __builtin_amdgcn_s_setprio(1); \
    _Pragma("unroll") for (int i_ = 0; i_ < 4; ++i_) \
    _Pragma("unroll") for (int j_ = 0; j_ < 2; ++j_) { \
      acc[QM][QN][i_][j_] = __builtin_amdgcn_mfma_f32_16x16x32_bf16( \
          aF[i_][0], bF[SET][j_][0], acc[QM][QN][i_][j_], 0, 0, 0); \
      acc[QM][QN][i_][j_] = __builtin_amdgcn_mfma_f32_16x16x32_bf16( \
          aF[i_][1], bF[SET][j_][1], acc[QM][QN][i_][j_], 0, 0, 0); \
    } \
    __builtin_amdgcn_s_setprio(0); \
  } while (0)
#define BARRIER() asm volatile("s_barrier" ::: "memory")
#define WAIT_LGKM0() do { asm volatile("s_waitcnt lgkmcnt(0)" ::: "memory"); \
    __builtin_amdgcn_sched_barrier(0); } while (0)
#define WAIT_VM(n) asm volatile("s_waitcnt vmcnt(" #n ")" ::: "memory")

__global__ __launch_bounds__(512, 2) void gemm_bf16_8ph(
    const unsigned short* __restrict__ A,
    const unsigned short* __restrict__ Bt,
    const float* __restrict__ b_enc,
    unsigned short* __restrict__ pre,
    int nOff) {
  __shared__ __align__(16) unsigned char lds[131072];

  const int t = threadIdx.x;
  // T1: bijective XCD swizzle (2048 blocks per launch, 2048 % 8 == 0), m-fastest.
  const int orig = blockIdx.x;
  const int swz = (orig & 7) * 256 + (orig >> 3);
  const int mBase = (swz & 15) << 8;                // 16 m-blocks
  const int nBase = nOff + ((swz >> 4) << 8);       // 128 n-blocks per launch

  const int lane = t & 63, wave = t >> 6;
  const int wm = wave >> 2, wn = wave & 3;          // 2x4 waves; 64x32 per quadrant
  const int frow = lane & 15, khalf = lane >> 4;

  // staging map: half-tile = 128 rows x 8 16B-chunks; thread t covers rows t>>3,
  // t>>3 + 64 at chunk t&7, LDS dest lane-linear (global_load_lds requirement).
  const int r0 = t >> 3, q0 = t & 7;
  const int kc0 = q0 ^ (r0 & 7);                    // inverse T2 swizzle on source
  const size_t aRow = (size_t)(mBase + r0) * D_IN + kc0 * 8;
  const size_t bRow = (size_t)(nBase + r0) * D_IN + kc0 * 8;

  // ds_read T2 swizzle: byte(row, chunk g) = row*128 + (g*16 ^ ((row&7)<<4))
  const int qswz = (khalf << 4) ^ ((frow & 7) << 4);
  const int aOffW = (wm * 64 + frow) * 128 + qswz;
  const int bOffW = (wn * 32 + frow) * 128 + qswz;

  floatx4 acc[2][2][4][2];
#pragma unroll
  for (int qm = 0; qm < 2; ++qm)
#pragma unroll
    for (int qn = 0; qn < 2; ++qn)
#pragma unroll
      for (int i = 0; i < 4; ++i)
#pragma unroll
        for (int j = 0; j < 2; ++j) acc[qm][qn][i][j] = (floatx4){0.f, 0.f, 0.f, 0.f};
  bf16x8 aF[4][2], bF[2][2][2];                     // bF[set][j][ks]

  // prologue: tile 0 into buf0; A0(1), B1(1) into buf1 (loop in-flight invariant).
  STAGE_A(0, 0, 0); STAGE_A(0, 1, 0); STAGE_B(0, 0, 0); STAGE_B(0, 1, 0);
  STAGE_A(1, 0, 1); STAGE_B(1, 1, 1);
  WAIT_VM(4);
  BARRIER();

#pragma unroll 1
  for (int it = 0; it < GNT / 2 - 1; ++it) {        // 15 steady iters (tiles 0..29)
    const int t0 = it * 2;
    // ph1: Q(0,0) tile t0 (buf0)
    LOAD_A(0, 0); LOAD_B(0, 0, 0);
    STAGE_A(t0 + 1, 1, 1);
    BARRIER(); WAIT_LGKM0(); MFMA_Q(0, 0, 0); BARRIER();
    // ph2: Q(0,1)
    LOAD_B(0, 1, 1);
    STAGE_B(t0 + 1, 0, 1);
    BARRIER(); WAIT_LGKM0(); MFMA_Q(0, 1, 1); BARRIER();
    // ph3: Q(1,1)
    LOAD_A(0, 1);
    STAGE_A(t0 + 2, 0, 0);
    BARRIER(); WAIT_LGKM0(); MFMA_Q(1, 1, 1); BARRIER();
    // ph4: Q(1,0) — no ds reads (bF set0 still holds B0); counted vmem wait
    STAGE_B(t0 + 2, 1, 0);
    WAIT_VM(4);
    BARRIER(); MFMA_Q(1, 0, 0); BARRIER();
    // ph5: Q(0,0) tile t0+1 (buf1)
    LOAD_A(1, 0); LOAD_B(1, 0, 0);
    STAGE_A(t0 + 2, 1, 0);
    BARRIER(); WAIT_LGKM0(); MFMA_Q(0, 0, 0); BARRIER();
    // ph6: Q(0,1)
    LOAD_B(1, 1, 1);
    STAGE_B(t0 + 2, 0, 0);
    BARRIER(); WAIT_LGKM0(); MFMA_Q(0, 1, 1); BARRIER();
    // ph7: Q(1,1)
    LOAD_A(1, 1);
    STAGE_A(t0 + 3, 0, 1);
    BARRIER(); WAIT_LGKM0(); MFMA_Q(1, 1, 1); BARRIER();
    // ph8: Q(1,0) — no ds reads; counted wait leaves [A0(t0+3), B1(t0+3)]
    STAGE_B(t0 + 3, 1, 1);
    WAIT_VM(4);
    BARRIER(); MFMA_Q(1, 0, 0); BARRIER();
  }

  // peeled final pair (tiles 30, 31)
  LOAD_A(0, 0); LOAD_B(0, 0, 0);
  STAGE_A(GNT - 1, 1, 1);
  BARRIER(); WAIT_LGKM0(); MFMA_Q(0, 0, 0); BARRIER();
  LOAD_B(0, 1, 1);
  STAGE_B(GNT - 1, 0, 1);
  BARRIER(); WAIT_LGKM0(); MFMA_Q(0, 1, 1); BARRIER();
  LOAD_A(0, 1);
  BARRIER(); WAIT_LGKM0(); MFMA_Q(1, 1, 1); BARRIER();
  WAIT_VM(0);
  BARRIER(); MFMA_Q(1, 0, 0); BARRIER();
  LOAD_A(1, 0); LOAD_B(1, 0, 0);
  BARRIER(); WAIT_LGKM0(); MFMA_Q(0, 0, 0); BARRIER();
  LOAD_B(1, 1, 1);
  BARRIER(); WAIT_LGKM0(); MFMA_Q(0, 1, 1); BARRIER();
  LOAD_A(1, 1);
  BARRIER(); WAIT_LGKM0(); MFMA_Q(1, 1, 1); BARRIER();
  WAIT_LGKM0(); MFMA_Q(1, 0, 0);

  // epilogue: C/D map col=lane&15, row=(lane>>4)*4+reg (m89-verified)
  const int ccol = lane & 15, crow = (lane >> 4) * 4;
#pragma unroll
  for (int Qn = 0; Qn < 2; ++Qn)
#pragma unroll
    for (int j = 0; j < 2; ++j) {
      int n = nBase + Qn * 128 + wn * 32 + j * 16 + ccol;
      float be = b_enc[n];
#pragma unroll
      for (int Qm = 0; Qm < 2; ++Qm)
#pragma unroll
        for (int i = 0; i < 4; ++i)
#pragma unroll
          for (int v = 0; v < 4; ++v) {
            int m = mBase + Qm * 128 + wm * 64 + i * 16 + crow + v;
            float val = acc[Qm][Qn][i][j][v] + be;
            val = val > 0.f ? val : 0.f;                 // relu
            pre[(size_t)m * D_SAE + n] = f2bf_rne(val);
          }
    }
}

#undef STAGE_A
#undef STAGE_B
#undef LOAD_A
#undef LOAD_B
#undef MFMA_Q

// ---------------- K4: per-row candidate selection (single pass) ----------------
// Top-64 of 65536 ~ N(0, 0.9^2) sits near 2.8, so values >= 2.0 (~900/row) are a
// safe superset. One read of the row: histogram >=2.0 (bins 16..63) AND buffer
// (idx,bits). Threshold bin b (cum>=64 from top); T = floor(b) - 0.09 margin.
// Fallback full re-scan if T < 2.0 or buffer overflow (unreachable for this data,
// >30 sigma; same robustness class as the previous 2-pass version).
__global__ __launch_bounds__(256) void select_cands(const unsigned short* __restrict__ pre,
                                                    int* __restrict__ cand_idx,
                                                    int* __restrict__ cand_cnt) {
  __shared__ int hist[64];
  __shared__ float sT;
  __shared__ int scnt, nbuf, sRescan;
  __shared__ int bufIdx[PREF];
  __shared__ unsigned bufBits[PREF];
  int row = blockIdx.x, t = threadIdx.x;
  for (int i = t; i < 64; i += 256) hist[i] = 0;
  if (t == 0) { scnt = 0; nbuf = 0; }
  __syncthreads();
  const uint4* p = (const uint4*)(pre + (size_t)row * D_SAE);   // 8192 x 16B
  for (int i = t; i < 8192; i += 256) {
    uint4 w = p[i];
    unsigned wd[4] = {w.x, w.y, w.z, w.w};
#pragma unroll
    for (int e = 0; e < 4; e++) {
      unsigned lo = wd[e] << 16, hi = wd[e] & 0xFFFF0000u;
      float f0 = __uint_as_float(lo), f1 = __uint_as_float(hi);
      if (f0 >= 2.0f) {
        atomicAdd(&hist[min((int)(lo >> 20) - 1008, 63)], 1);
        int q = atomicAdd(&nbuf, 1);
        if (q < PREF) { bufIdx[q] = i * 8 + e * 2; bufBits[q] = lo; }
      }
      if (f1 >= 2.0f) {
        atomicAdd(&hist[min((int)(hi >> 20) - 1008, 63)], 1);
        int q = atomicAdd(&nbuf, 1);
        if (q < PREF) { bufIdx[q] = i * 8 + e * 2 + 1; bufBits[q] = hi; }
      }
    }
  }
  __syncthreads();
  if (t == 0) {
    int cum = 0, b = 63;
    for (; b >= 16; b--) { cum += hist[b]; if (cum >= K_TOP) break; }
    if (b < 16) b = 16;
    // bin floor minus margin: covers bf16-GEMM (~0.03 max) + bf16-store error
    float T = __uint_as_float((unsigned)(b + 1008) << 20) - 0.09f;
    sT = T;
    sRescan = (nbuf > PREF || T < 2.0f) ? 1 : 0;
  }
  __syncthreads();
  float T = sT;
  if (!sRescan) {
    int nb = nbuf;
    for (int i = t; i < nb; i += 256) {
      float v = __uint_as_float(bufBits[i]);
      if (v >= T) { int q = atomicAdd(&scnt, 1); if (q < MAXC) cand_idx[(size_t)row * MAXC + q] = bufIdx[i]; }
    }
  } else {
    for (int i = t; i < 8192; i += 256) {
      uint4 w = p[i];
      unsigned wd[4] = {w.x, w.y, w.z, w.w};
#pragma unroll
      for (int e = 0; e < 4; e++) {
        unsigned lo = wd[e] << 16, hi = wd[e] & 0xFFFF0000u;
        float f0 = __uint_as_float(lo), f1 = __uint_as_float(hi);
        if (f0 >= T) { int q = atomicAdd(&scnt, 1); if (q < MAXC) cand_idx[(size_t)row * MAXC + q] = i * 8 + e * 2; }
        if (f1 >= T) { int q = atomicAdd(&scnt, 1); if (q < MAXC) cand_idx[(size_t)row * MAXC + q] = i * 8 + e * 2 + 1; }
      }
    }
  }
  __syncthreads();
  if (t == 0) cand_cnt[row] = min(scnt, MAXC);
}

// ---------------- K5: bucket candidates by 128-col tile ----------------
__global__ void zero_counts(int* tileCnt, int* cursor) {
  int i = blockIdx.x * 256 + threadIdx.x;
  if (i < NTILE) { tileCnt[i] = 0; cursor[i] = 0; }
}
__global__ __launch_bounds__(256) void count_pairs(const int* __restrict__ cand_idx,
                                                   const int* __restrict__ cand_cnt,
                                                   int* __restrict__ tileCnt) {
  int row = blockIdx.x, cnt = cand_cnt[row];
  for (int s = threadIdx.x; s < cnt; s += 256)
    atomicAdd(&tileCnt[cand_idx[(size_t)row * MAXC + s] >> 7], 1);
}
__global__ void scan_tiles(const int* __restrict__ tileCnt, int* __restrict__ tileOff) {
  if (threadIdx.x == 0) {
    int acc = 0;
    for (int i = 0; i < NTILE; i++) { tileOff[i] = acc; acc += tileCnt[i]; }
  }
}
__global__ __launch_bounds__(256) void scatter_pairs(const int* __restrict__ cand_idx,
                                                     const int* __restrict__ cand_cnt,
                                                     const int* __restrict__ tileOff,
                                                     int* __restrict__ cursor,
                                                     unsigned long long* __restrict__ pairs) {
  int row = blockIdx.x, cnt = cand_cnt[row];
  for (int s = threadIdx.x; s < cnt; s += 256) {
    int col = cand_idx[(size_t)row * MAXC + s];
    int tl = col >> 7;
    int q = atomicAdd(&cursor[tl], 1);
    pairs[tileOff[tl] + q] =
        ((unsigned long long)row << 32) | ((unsigned long long)(unsigned)col << 16) | (unsigned)s;
  }
}

// ---------------- K6: exact fp64 recompute of candidates ----------------
__global__ __launch_bounds__(256) void recompute_exact(const float* __restrict__ W,
                                                       const float* __restrict__ xc,
                                                       const float* __restrict__ b_enc,
                                                       const unsigned long long* __restrict__ pairs,
                                                       const int* __restrict__ tileCnt,
                                                       const int* __restrict__ tileOff,
                                                       double* __restrict__ candVal) {
  __shared__ float Wl[512 * 17];     // 512 k x 16 cols, pad 17 (bank-conflict free)
  __shared__ int lists[8][256];
  __shared__ int lcnt[8];
  __shared__ double pacc[256];
  int tile = blockIdx.x, t = threadIdx.x;
  int n0 = tile << 7;
  int nP = tileCnt[tile], base = tileOff[tile];
  if (t < 8) lcnt[t] = 0;
  __syncthreads();
  for (int i = t; i < nP; i += 256) {
    int col = (int)((pairs[base + i] >> 16) & 0xFFFF);
    int st = (col >> 4) & 7;
    int q = atomicAdd(&lcnt[st], 1);
    if (q < 256) lists[st][q] = i;
  }
  int lane = t & 63, wave = t >> 6;
  for (int st = 0; st < 8; st++) {
    __syncthreads();
    int cnt = min(lcnt[st], 256);
    for (int i = t; i < cnt; i += 256) pacc[i] = 0.0;
    for (int kc = 0; kc < 4; kc++) {
      __syncthreads();
      for (int e = t; e < 512 * 16; e += 256) {
        int k = e >> 4, c = e & 15;
        Wl[k * 17 + c] = W[(size_t)(kc * 512 + k) * D_SAE + n0 + st * 16 + c];
      }
      __syncthreads();
      for (int pi = wave; pi < cnt; pi += 4) {
        unsigned long long u = pairs[base + lists[st][pi]];
        int row = (int)(u >> 32);
        int cc = (int)((u >> 16) & 15);
        const float* xr = xc + (size_t)row * D_IN + kc * 512;
        double a = 0.0;
#pragma unroll
        for (int j = 0; j < 8; j++) {
          int k = lane + j * 64;
          a += (double)xr[k] * (double)Wl[k * 17 + cc];
        }
#pragma unroll
        for (int off = 32; off > 0; off >>= 1) a += __shfl_down(a, off, 64);
        if (lane == 0) pacc[pi] += a;
      }
    }
    __syncthreads();
    for (int i = t; i < cnt; i += 256) {
      unsigned long long u = pairs[base + lists[st][i]];
      int row = (int)(u >> 32);
      int col = (int)((u >> 16) & 0xFFFF);
      int slot = (int)(u & 0xFFFF);
      candVal[(size_t)row * MAXC + slot] = pacc[i] + (double)b_enc[col];
    }
  }
}

// ---------------- K7: per-row bitonic top-64 on exact values ----------------
__global__ __launch_bounds__(256) void topk_select(const int* __restrict__ cand_idx,
                                                   const int* __restrict__ cand_cnt,
                                                   const double* __restrict__ candVal,
                                                   int* __restrict__ topIdx,
                                                   float* __restrict__ topVal) {
  __shared__ double sv[MAXC];
  __shared__ int si[MAXC];
  int row = blockIdx.x, t = threadIdx.x;
  int cnt = cand_cnt[row];
  for (int i = t; i < MAXC; i += 256) {
    if (i < cnt) { sv[i] = candVal[(size_t)row * MAXC + i]; si[i] = cand_idx[(size_t)row * MAXC + i]; }
    else         { sv[i] = -1.0e300; si[i] = 0x7FFFFFFF; }
  }
  for (int ksz = 2; ksz <= MAXC; ksz <<= 1) {
    for (int j = ksz >> 1; j > 0; j >>= 1) {
      __syncthreads();
      for (int e = t; e < MAXC; e += 256) {
        int p = e ^ j;
        if (p > e) {
          double v0 = sv[e], v1 = sv[p];
          int i0 = si[e], i1 = si[p];
          bool before = (v0 > v1) || (v0 == v1 && i0 < i1);   // e precedes p desc
          bool desc = ((e & ksz) == 0);
          if (desc ? !before : before) { sv[e] = v1; sv[p] = v0; si[e] = i1; si[p] = i0; }
        }
      }
    }
  }
  __syncthreads();
  if (t < K_TOP) {
    double v = sv[t];
    topIdx[(size_t)row * K_TOP + t] = si[t];
    topVal[(size_t)row * K_TOP + t] = (float)(v > 0.0 ? v : 0.0);   // relu
  }
}

// ---------------- K8: zero output row + scatter ----------------
__global__ __launch_bounds__(256) void write_out(const int* __restrict__ topIdx,
                                                 const float* __restrict__ topVal,
                                                 float* __restrict__ out) {
  int row = blockIdx.x, t = threadIdx.x;
  float4* o = (float4*)(out + (size_t)row * D_SAE);
  float4 z = {0.f, 0.f, 0.f, 0.f};
  for (int i = t; i < D_SAE / 4; i += 256) o[i] = z;
  __syncthreads();
  if (t < K_TOP) {
    int idx = topIdx[(size_t)row * K_TOP + t];
    if ((unsigned)idx < (unsigned)D_SAE)
      out[(size_t)row * D_SAE + idx] = topVal[(size_t)row * K_TOP + t];
  }
}

extern "C" void kernel_launch(void* const* d_in, const int* in_sizes, int n_in,
                              void* d_out, int out_size, void* d_ws, size_t ws_size,
                              hipStream_t stream) {
  const float* x     = (const float*)d_in[0];
  const float* W     = (const float*)d_in[1];
  const float* b_enc = (const float*)d_in[2];
  const float* b_dec = (const float*)d_in[3];
  // d_in[4] = k (==64, fixed by setup_inputs) -> compile-time K_TOP

  // big scratch carved out of d_out (1 GiB), lifetime-disjoint:
  char* ob = (char*)d_out;
  unsigned short* pre  = (unsigned short*)ob;                        // approx pre bf16
  unsigned short* Wt   = (unsigned short*)(ob + (size_t)536870912);  // W^T bf16
  float* xc            = (float*)(ob + (size_t)805306368);           // x-b_dec fp32
  unsigned short* x_bf = (unsigned short*)(ob + (size_t)838860800);  // 16 MiB bf16 x

  char* wsb = (char*)d_ws;                                           // ~43 MiB used
  int*    cand_idx = (int*)wsb;                                      // 8 MiB
  double* candVal  = (double*)(wsb + ((size_t)8 << 20));             // 16 MiB
  unsigned long long* pairs = (unsigned long long*)(wsb + ((size_t)24 << 20)); // 16 MiB
  int* cand_cnt = (int*)(wsb + ((size_t)40 << 20));                  // 16 KiB
  int* tileCnt  = (int*)(wsb + ((size_t)40 << 20) + 65536);
  int* tileOff  = tileCnt + NTILE;
  int* cursor   = tileOff + NTILE;
  int* topIdx   = (int*)(wsb + ((size_t)41 << 20));                  // 1 MiB
  float* topVal = (float*)(wsb + ((size_t)42 << 20));                // 1 MiB

  prep_x<<<8192, 256, 0, stream>>>(x, b_dec, x_bf, xc);
  transpose_w<<<dim3(1024, 32), 256, 0, stream>>>(W, Wt);
  gemm_bf16_8ph<<<2048, 512, 0, stream>>>(x_bf, Wt, b_enc, pre, 0);
  gemm_bf16_8ph<<<2048, 512, 0, stream>>>(x_bf, Wt, b_enc, pre, D_SAE / 2);
  select_cands<<<B_ROWS, 256, 0, stream>>>(pre, cand_idx, cand_cnt);
  zero_counts<<<2, 256, 0, stream>>>(tileCnt, cursor);
  count_pairs<<<B_ROWS, 256, 0, stream>>>(cand_idx, cand_cnt, tileCnt);
  scan_tiles<<<1, 64, 0, stream>>>(tileCnt, tileOff);
  scatter_pairs<<<B_ROWS, 256, 0, stream>>>(cand_idx, cand_cnt, tileOff, cursor, pairs);
  recompute_exact<<<NTILE, 256, 0, stream>>>(W, xc, b_enc, pairs, tileCnt, tileOff, candVal);
  topk_select<<<B_ROWS, 256, 0, stream>>>(cand_idx, cand_cnt, candVal, topIdx, topVal);
  write_out<<<B_ROWS, 256, 0, stream>>>(topIdx, topVal, (float*)d_out);
}